// Round 6
// baseline (359.520 us; speedup 1.0000x reference)
//
#include <hip/hip_runtime.h>
#include <stdint.h>

typedef _Float16 f16;
typedef _Float16 f16x4 __attribute__((ext_vector_type(4)));
typedef _Float16 f16x8 __attribute__((ext_vector_type(8)));
typedef float f32x4 __attribute__((ext_vector_type(4)));
typedef unsigned long long u64;

#define D_DIM 256
#define K_CB 4096
#define N_ROWS 65536
#define BM 64
#define BN 128
#define N_TILES 32
#define LOSS_OFF 16777216
#define IDS_OFF 16777217
#define MAX_FIX 4096

// workspace layout (bytes)
#define WS_CHI 0            // 4096*256 f16 = 2 MB
#define WS_CN 2097152       // 4096 f32 = 16 KB
#define WS_CNT 2113536      // u32 counter (+pad to 64)
#define WS_ROWS 2113600     // 4096 u32 = 16 KB
#define WS_SLOTS 2129984    // 4096 u64 = 32 KB

// LDS layout (k_main, 49152 B dynamic -> 3 blocks/CU):
//   [0,32768)       A : 64 rows x 256 f16 (-2*z), 16B blocks XOR-swizzled by (row&7)
//   [32768,49152)   B dbuf: 2 x 8192 B (128 entries x 32 f16), swizzled by ((e>>1)&3)
//   B region reused after main loop: mk1/mk2/mk3 u32[64], then loss scratch.

// direct-to-LDS 16B async copy (per-lane global addr, wave-uniform LDS base + lane*16)
#define GL_LDS(g, s_) __builtin_amdgcn_global_load_lds( \
    (const __attribute__((address_space(1))) void*)(g), \
    (__attribute__((address_space(3))) void*)(s_), 16, 0, 0)

static __device__ __forceinline__ uint32_t f2u(float x) { union { float f; uint32_t u; } c; c.f = x; return c.u; }
static __device__ __forceinline__ float u2f(uint32_t x) { union { float f; uint32_t u; } c; c.u = x; return c.f; }
static __device__ __forceinline__ uint32_t umin_(uint32_t a, uint32_t b) { return a < b ? a : b; }
static __device__ __forceinline__ uint32_t umax_(uint32_t a, uint32_t b) { return a > b ? a : b; }
static __device__ __forceinline__ u64 d2u(double x) { union { double d; u64 u; } c; c.d = x; return c.u; }
// single-instruction unsigned median-of-3 (VOP3, gfx9+)
static __device__ __forceinline__ uint32_t med3u(uint32_t a, uint32_t b, uint32_t c) {
    uint32_t d;
    asm("v_med3_u32 %0, %1, %2, %3" : "=v"(d) : "v"(a), "v"(b), "v"(c));
    return d;
}

// ---------------- K0: codebook -> f16 hi + fp32 row norms; init cnt/slots/loss ----
__global__ __launch_bounds__(256) void k_prep_cb(const float* __restrict__ cb,
                                                 f16* __restrict__ chi,
                                                 float* __restrict__ cn,
                                                 uint32_t* __restrict__ cnt,
                                                 u64* __restrict__ slots,
                                                 float* __restrict__ loss_slot) {
    const int tid = threadIdx.x;
    const int w = tid >> 6, l = tid & 63;
    const int row = blockIdx.x * 4 + w;            // one wave per codebook row
    const float4 v = ((const float4*)cb)[row * 64 + l];
    f16x4 h4;
    h4[0] = (f16)v.x; h4[1] = (f16)v.y; h4[2] = (f16)v.z; h4[3] = (f16)v.w;
    float ss = v.x * v.x + v.y * v.y + v.z * v.z + v.w * v.w;
#pragma unroll
    for (int m = 32; m >= 1; m >>= 1) ss += __shfl_xor(ss, m);
    ((f16x4*)chi)[row * 64 + l] = h4;
    if (l == 0) cn[row] = ss;
    if (tid < 4) slots[blockIdx.x * 4 + tid] = 0xFFFFFFFFFFFFFFFFull;  // 1024 x 4 = 4096
    if (blockIdx.x == 0 && tid == 0) { *cnt = 0; *loss_slot = 0.0f; }
}

// ---------------- K1: 1-pass f16 GEMM (A = -2*z_hi, C-init = cn+64) + top-3 + rescore ----
// wave w owns rows [w*16, w*16+16); each wave covers all 128 columns of the tile.
__global__ __launch_bounds__(256) void k_main(const float* __restrict__ z,
                                              const float* __restrict__ cb,
                                              const f16* __restrict__ chi,
                                              const float* __restrict__ cn,
                                              uint32_t* __restrict__ cnt,
                                              uint32_t* __restrict__ rows,
                                              float* __restrict__ out) {
    extern __shared__ char smem[];
    const int tid = threadIdx.x;
    const int w = tid >> 6, l = tid & 63;
    const int l15 = l & 15, qh = l >> 4;
    const int blk = blockIdx.x;
    const float* ztile = z + (size_t)blk * (BM * D_DIM);

    // ---- stage A once: fp32 -> f16(-2z), swizzled ----
#pragma unroll 4
    for (int p = 0; p < 16; ++p) {
        const int r = p * 4 + w;
        const float4 v = ((const float4*)ztile)[r * 64 + l];
        f16x4 h4;
        h4[0] = (f16)(v.x * -2.0f); h4[1] = (f16)(v.y * -2.0f);
        h4[2] = (f16)(v.z * -2.0f); h4[3] = (f16)(v.w * -2.0f);
        const int addr = r * 512 + ((((l >> 1) ^ (r & 7))) << 4) + ((l & 1) << 3);
        *(f16x4*)(smem + addr) = h4;
    }

    // ---- codebook-norm prefetch (tile 0) ----
    float cnNext[8];
#pragma unroll
    for (int j = 0; j < 8; ++j) cnNext[j] = cn[j * 16 + l15];

    // ---- B staging constants ----
    const int e0 = tid >> 2;
    const int q0 = (tid & 3) ^ ((e0 >> 1) & 3);
    const int offE = e0 * 256 + q0 * 8;

    // ---- fragment read address constants ----
    const int rA = w * 16 + l15;                   // this wave's A row for its fragment
    const int rowb = rA * 512, rs = rA & 7;
    int bcon[8];
#pragma unroll
    for (int j = 0; j < 8; ++j) {
        const int e = j * 16 + l15;
        bcon[j] = e * 64 + ((qh ^ ((e >> 1) & 3)) << 4);
    }

    // prologue: B chunk for step 0 into buf0
    {
        const f16* gh = chi + offE;
        char* bb = smem + 32768 + w * 1024;
        GL_LDS(gh, bb);
        GL_LDS(gh + 16384, bb + 4096);
    }

    uint32_t k1[4], k2[4], k3[4];
#pragma unroll
    for (int s = 0; s < 4; ++s) { k1[s] = 0xFFFFFFFFu; k2[s] = 0xFFFFFFFFu; k3[s] = 0xFFFFFFFFu; }
    f32x4 acc[8];

    for (int tile = 0; tile < N_TILES; ++tile) {
        // C-init = cn + 64 -> final acc = cn + 64 - 2*z.c  (positive; key-packable)
#pragma unroll
        for (int j = 0; j < 8; ++j) {
            const float base = cnNext[j] + 64.0f;
            acc[j] = (f32x4){base, base, base, base};
        }
#pragma unroll
        for (int kc = 0; kc < 8; ++kc) {
            __syncthreads();
            const int step = tile * 8 + kc;
            if (step + 1 < N_TILES * 8) {
                const int nt = (step + 1) >> 3, nk = (step + 1) & 7;
                const f16* gh = chi + nt * (BN * D_DIM) + nk * 32 + offE;
                char* bb = smem + 32768 + ((step + 1) & 1) * 8192 + w * 1024;
                GL_LDS(gh, bb);
                GL_LDS(gh + 16384, bb + 4096);
            }
            if (kc == 0) {                          // prefetch next tile's cnorms
                const int tn = (tile + 1 < N_TILES) ? tile + 1 : tile;
#pragma unroll
                for (int j = 0; j < 8; ++j)
                    cnNext[j] = cn[tn * BN + j * 16 + l15];
            }
            const char* bbase = smem + 32768 + (step & 1) * 8192;
            const int t = ((kc << 2) + qh) ^ rs;
            const f16x8 ah = *(const f16x8*)(smem + rowb + (t << 4));
            f16x8 bh[8];
#pragma unroll
            for (int j = 0; j < 8; ++j) bh[j] = *(const f16x8*)(bbase + bcon[j]);
#pragma unroll
            for (int j = 0; j < 8; ++j)
                acc[j] = __builtin_amdgcn_mfma_f32_16x16x32_f16(ah, bh[j], acc[j], 0, 0, 0);
        }
        // epilogue: key = (bits(acc) & ~0xFFF) | col; 4-op med3 top-3 insert
        const uint32_t colb = (uint32_t)(tile * BN + l15);
#pragma unroll
        for (int j = 0; j < 8; ++j) {
            const uint32_t col = colb + j * 16;
#pragma unroll
            for (int rr = 0; rr < 4; ++rr) {
                const uint32_t kk = (f2u(acc[j][rr]) & 0xFFFFF000u) | col;
                k3[rr] = med3u(k2[rr], k3[rr], kk);   // 3rd-smallest (uses old k2)
                k2[rr] = med3u(k1[rr], k2[rr], kk);   // 2nd-smallest (uses old k1)
                k1[rr] = umin_(k1[rr], kk);
            }
        }
    }

    // ---- merge sorted triples across the 16 column-lanes of each row ----
#pragma unroll
    for (int s = 0; s < 4; ++s) {
        uint32_t a1 = k1[s], a2 = k2[s], a3 = k3[s];
#pragma unroll
        for (int m = 1; m <= 8; m <<= 1) {
            const uint32_t b1 = (uint32_t)__shfl_xor((int)a1, m);
            const uint32_t b2 = (uint32_t)__shfl_xor((int)a2, m);
            const uint32_t b3 = (uint32_t)__shfl_xor((int)a3, m);
            const uint32_t x = umax_(a1, b1);
            const uint32_t m2v = umin_(a2, b2), M2 = umax_(a2, b2);
            const uint32_t m3v = umin_(a3, b3);
            a1 = umin_(a1, b1);
            a2 = umin_(x, m2v);
            a3 = umin_(umin_(umax_(x, m2v), M2), m3v);
        }
        k1[s] = a1; k2[s] = a2; k3[s] = a3;
    }
    __syncthreads();                               // B region reusable now
    uint32_t* mk = (uint32_t*)(smem + 32768);      // mk1[64] | mk2[64] | mk3[64]
    double* lossW = (double*)(smem + 32768 + 768); // 8B aligned
    if (l15 == 0) {                                // each row owned by exactly one wave
#pragma unroll
        for (int rr = 0; rr < 4; ++rr) {
            const int row = w * 16 + qh * 4 + rr;
            mk[row] = k1[rr]; mk[64 + row] = k2[rr]; mk[128 + row] = k3[rr];
        }
    }
    __syncthreads();

    // ---- gather + exact f64 rescore of top-2 + certification + loss ----
    double lossAcc = 0.0;
    for (int it = 0; it < 16; ++it) {
        const int row = it * 4 + w;                // one wave per row
        const uint32_t K1 = mk[row], K2 = mk[64 + row], K3 = mk[128 + row];
        const int col1 = (int)(K1 & 4095u), col2 = (int)(K2 & 4095u);
        const float4 c1 = ((const float4*)cb)[col1 * 64 + l];
        const float4 c2 = ((const float4*)cb)[col2 * 64 + l];
        const float4 z4 = ((const float4*)ztile)[row * 64 + l];
        double e1, e2;
        {
            const double dx1 = (double)c1.x - z4.x, dy1 = (double)c1.y - z4.y;
            const double dz1 = (double)c1.z - z4.z, dw1 = (double)c1.w - z4.w;
            e1 = dx1 * dx1 + dy1 * dy1 + dz1 * dz1 + dw1 * dw1;
            const double dx2 = (double)c2.x - z4.x, dy2 = (double)c2.y - z4.y;
            const double dz2 = (double)c2.z - z4.z, dw2 = (double)c2.w - z4.w;
            e2 = dx2 * dx2 + dy2 * dy2 + dz2 * dz2 + dw2 * dw2;
        }
        float zn2 = z4.x * z4.x + z4.y * z4.y + z4.z * z4.z + z4.w * z4.w;
#pragma unroll
        for (int m = 32; m >= 1; m >>= 1) {
            e1 += __shfl_xor(e1, m);
            e2 += __shfl_xor(e2, m);
            zn2 += __shfl_xor(zn2, m);
        }
        const bool take1 = (e1 < e2) || (e1 == e2 && col1 <= col2);
        const float4 cw = take1 ? c1 : c2;
        ((float4*)out)[(blk * BM + row) * 64 + l] = cw;
        if (l == 0) {
            const int colw = take1 ? col1 : col2;
            const double ew = take1 ? e1 : e2;
            out[IDS_OFF + blk * BM + row] = (float)colw;
            lossAcc += ew;
            // key = cn - 2M + 64 -> d2 lower bound of 3rd-best = key + zn - 64
            const float d3 = u2f(K3 & 0xFFFFF000u) + zn2 - 64.0f;
            const float eps = 0.006f * sqrtf(zn2) + 0.01f;
            if (!((float)ew < d3 - eps)) {
                const uint32_t e = atomicAdd(cnt, 1u);
                if (e < MAX_FIX) rows[e] = (uint32_t)(blk * BM + row);
            }
        }
    }
    if (l == 0) lossW[w] = lossAcc;
    __syncthreads();
    if (tid == 0) {
        const double tot = (lossW[0] + lossW[1] + lossW[2] + lossW[3]) * (1.25 / 16777216.0);
        atomicAdd(out + LOSS_OFF, (float)tot);
    }
}

// ---------------- K2a: parallel exact scan for flagged rows (16 blocks per row) ----
__global__ __launch_bounds__(256) void k_fix_scan(const float* __restrict__ z,
                                                  const float* __restrict__ cb,
                                                  const uint32_t* __restrict__ cnt,
                                                  const uint32_t* __restrict__ rows,
                                                  u64* __restrict__ slots) {
    __shared__ float zrow[256];
    __shared__ u64 wmin[4];
    const int tid = threadIdx.x;
    const int w = tid >> 6, l = tid & 63;
    const int chunk = blockIdx.x & 15;
    uint32_t n = *cnt; if (n > MAX_FIX) n = MAX_FIX;
    for (uint32_t e = blockIdx.x >> 4; e < n; e += 64) {
        const int row = (int)rows[e];
        __syncthreads();                           // protect zrow across iterations
        if (tid < 64) ((float4*)zrow)[tid] = ((const float4*)z)[row * 64 + tid];
        __syncthreads();
        const int c = chunk * 256 + tid;
        const float4* crow = (const float4*)(cb + (size_t)c * 256);
        double s = 0.0;
        for (int q = 0; q < 64; ++q) {
            const float4 cv = crow[q];
            const float4 zv = ((const float4*)zrow)[q];
            const double dx = (double)cv.x - zv.x, dy = (double)cv.y - zv.y;
            const double dz = (double)cv.z - zv.z, dw = (double)cv.w - zv.w;
            s += dx * dx + dy * dy + dz * dz + dw * dw;
        }
        u64 key = (d2u(s) & 0xFFFFFFFFFFFFF000ull) | (u64)c;  // d2 trunc + col tiebreak
#pragma unroll
        for (int m = 32; m >= 1; m >>= 1) {
            const u64 o = __shfl_xor(key, m);
            if (o < key) key = o;
        }
        if (l == 0) wmin[w] = key;
        __syncthreads();
        if (tid == 0) {
            u64 k = wmin[0];
            if (wmin[1] < k) k = wmin[1];
            if (wmin[2] < k) k = wmin[2];
            if (wmin[3] < k) k = wmin[3];
            atomicMin(&slots[e], k);
        }
    }
}

// ---------------- K2b: patch ids / z_q / loss for flagged rows ----
__global__ __launch_bounds__(256) void k_fix_patch(const float* __restrict__ z,
                                                   const float* __restrict__ cb,
                                                   const uint32_t* __restrict__ cnt,
                                                   const uint32_t* __restrict__ rows,
                                                   const u64* __restrict__ slots,
                                                   float* __restrict__ out) {
    const int tid = threadIdx.x;
    uint32_t n = *cnt; if (n > MAX_FIX) n = MAX_FIX;
    for (uint32_t e = blockIdx.x; e < n; e += 256) {
        const int row = (int)rows[e];
        const int newc = (int)(slots[e] & 4095ull);
        const int oldc = (int)out[IDS_OFF + row];
        if (newc == oldc) continue;                // uniform across block
        double dOld = 0.0, dNew = 0.0;
        if (tid < 64) {
            const float4 zv = ((const float4*)z)[row * 64 + tid];
            const float4 co = ((const float4*)cb)[oldc * 64 + tid];
            const float4 cn4 = ((const float4*)cb)[newc * 64 + tid];
            const double ax = (double)co.x - zv.x, ay = (double)co.y - zv.y;
            const double az = (double)co.z - zv.z, aw = (double)co.w - zv.w;
            dOld = ax * ax + ay * ay + az * az + aw * aw;
            const double bx = (double)cn4.x - zv.x, by = (double)cn4.y - zv.y;
            const double bz = (double)cn4.z - zv.z, bw = (double)cn4.w - zv.w;
            dNew = bx * bx + by * by + bz * bz + bw * bw;
            ((float4*)out)[row * 64 + tid] = cn4;  // patch z_q
        }
#pragma unroll
        for (int m = 32; m >= 1; m >>= 1) {
            dOld += __shfl_xor(dOld, m);
            dNew += __shfl_xor(dNew, m);
        }
        if (tid == 0) {
            out[IDS_OFF + row] = (float)newc;
            atomicAdd(out + LOSS_OFF, (float)((dNew - dOld) * (1.25 / 16777216.0)));
        }
    }
}

extern "C" void kernel_launch(void* const* d_in, const int* in_sizes, int n_in,
                              void* d_out, int out_size, void* d_ws, size_t ws_size,
                              hipStream_t stream) {
    (void)in_sizes; (void)n_in; (void)out_size; (void)ws_size;
    const float* z = (const float*)d_in[0];
    const float* cb = (const float*)d_in[1];
    float* out = (float*)d_out;
    char* ws = (char*)d_ws;
    f16* chi = (f16*)(ws + WS_CHI);
    float* cn = (float*)(ws + WS_CN);
    uint32_t* cnt = (uint32_t*)(ws + WS_CNT);
    uint32_t* rows = (uint32_t*)(ws + WS_ROWS);
    u64* slots = (u64*)(ws + WS_SLOTS);

    k_prep_cb<<<K_CB / 4, 256, 0, stream>>>(cb, chi, cn, cnt, slots, out + LOSS_OFF);
    k_main<<<N_ROWS / BM, 256, 49152, stream>>>(z, cb, chi, cn, cnt, rows, out);
    k_fix_scan<<<1024, 256, 0, stream>>>(z, cb, cnt, rows, slots);
    k_fix_patch<<<256, 256, 0, stream>>>(z, cb, cnt, rows, slots, out);
}